// Round 3
// baseline (1599.412 us; speedup 1.0000x reference)
//
#include <hip/hip_runtime.h>
#include <stdint.h>

// DetectionLoss for B=16, N=884736 (fixed problem shape).
// Output: [cls_pos_loss, cls_neg_loss] (2 x f32).
//
// Strategy:
//  passA (big streaming pass): per element compute JAX threefry-partitionable
//    random key (23-bit), accumulate positive loss/count, and append negative
//    "candidates" (key >= THRESH_KEY, ~1.45% tail => ~12.8k/sample, always
//    >= 10000 and <= CAP with >20 sigma margin) to workspace.
//  passB (16 blocks): exact top-10000-by-key selection over candidates
//    (binary search on 23-bit key in LDS, boundary ties broken by lowest
//    index, matching XLA top_k stability), sum their losses; exact top-k
//    fallback by loss-value threshold for the (never taken here) k<10000 case.
//  passC: final per-sample normalization + mean over batch.
//
// ws_size is checked: candidate capacity is clamped to what fits (defensive —
// an OOB append could fault the device and kill the container).

#define BATCH 16
#define NPTS 884736u
#define THRESH_KEY 8266976u   // keep keys >= this (tail fraction 0.01450)
#define CAP 15360u            // candidate capacity per sample (mean ~12825, sd ~112)
#define BCAP 64
#define KSEL 10000u

struct KeyPairs { unsigned k[2 * BATCH]; };

__host__ __device__ __forceinline__ void tf2x32(unsigned k0, unsigned k1,
                                                unsigned x0, unsigned x1,
                                                unsigned& o0, unsigned& o1)
{
  // JAX threefry2x32 (20 rounds), matches jax/_src/prng.py lowering.
  unsigned ks0 = k0, ks1 = k1, ks2 = k0 ^ k1 ^ 0x1BD11BDAu;
  x0 += ks0; x1 += ks1;
#define TF_R(r) { x0 += x1; x1 = (x1 << (r)) | (x1 >> (32 - (r))); x1 ^= x0; }
  TF_R(13) TF_R(15) TF_R(26) TF_R(6)
  x0 += ks1; x1 += ks2 + 1u;
  TF_R(17) TF_R(29) TF_R(16) TF_R(24)
  x0 += ks2; x1 += ks0 + 2u;
  TF_R(13) TF_R(15) TF_R(26) TF_R(6)
  x0 += ks0; x1 += ks1 + 3u;
  TF_R(17) TF_R(29) TF_R(16) TF_R(24)
  x0 += ks1; x1 += ks2 + 4u;
  TF_R(13) TF_R(15) TF_R(26) TF_R(6)
  x0 += ks2; x1 += ks0 + 5u;
#undef TF_R
  o0 = x0; o1 = x1;
}

__device__ __forceinline__ float lossf(float x, float t, float m)
{
  float p = 1.0f / (1.0f + expf(-x));
  p = fminf(fmaxf(p, 1e-4f), 1.0f - 1e-4f);
  bool is_pos = (t == 1.0f);
  float alpha = is_pos ? 0.75f : 0.25f;
  float pw = is_pos ? (1.0f - p) : p;
  float bce = fmaxf(x, 0.0f) - x * t + log1pf(expf(-fabsf(x)));
  float L = (m == 0.0f) ? alpha * pw * pw * bce : 0.0f;
  if (is_pos && p < 0.8f) L *= 4.0f;                 // FN upweight (pos only)
  if (!is_pos && p > 0.5f) {                          // hard-FP upweight (neg only)
    float w = 1.5f + fminf(fmaxf((p - 0.5f) * 5.0f, 0.0f), 1.0f) * 0.5f;
    L *= w;
  }
  return L;
}

__global__ __launch_bounds__(256) void passA(
    const float* __restrict__ pred, const float* __restrict__ target,
    const float* __restrict__ mask,
    float* __restrict__ pos_sum, unsigned* __restrict__ npos_arr,
    unsigned* __restrict__ cand_cnt, unsigned* __restrict__ g_keys,
    unsigned* __restrict__ g_idxs, float* __restrict__ g_loss,
    unsigned cap, KeyPairs kp)
{
  const int b = blockIdx.y;
  const unsigned i0 = (blockIdx.x * 256u + threadIdx.x) * 4u;
  const size_t off = (size_t)b * NPTS + i0;
  const unsigned k0 = kp.k[2 * b], k1 = kp.k[2 * b + 1];

  float4 t4 = *reinterpret_cast<const float4*>(target + off);
  float tv[4] = { t4.x, t4.y, t4.z, t4.w };

  unsigned keyv[4];
#pragma unroll
  for (int r = 0; r < 4; ++r) {
    unsigned o0, o1;
    tf2x32(k0, k1, 0u, i0 + (unsigned)r, o0, o1);   // partitionable: counter (0, i)
    keyv[r] = (o0 ^ o1) >> 9;                       // 23-bit uniform order key
  }

  bool isposv[4], candv[4];
  bool any = false;
#pragma unroll
  for (int r = 0; r < 4; ++r) {
    isposv[r] = (tv[r] == 1.0f);
    candv[r] = (tv[r] == 0.0f) && (keyv[r] >= THRESH_KEY);
    any |= (isposv[r] | candv[r]);
  }

  float pv[4] = {0.f,0.f,0.f,0.f}, mv[4] = {0.f,0.f,0.f,0.f};
  if (any) {
    float4 p4 = *reinterpret_cast<const float4*>(pred + off);
    float4 m4 = *reinterpret_cast<const float4*>(mask + off);
    pv[0]=p4.x; pv[1]=p4.y; pv[2]=p4.z; pv[3]=p4.w;
    mv[0]=m4.x; mv[1]=m4.y; mv[2]=m4.z; mv[3]=m4.w;
  }

#pragma unroll
  for (int r = 0; r < 4; ++r) {
    float L = 0.0f;
    if (isposv[r] | candv[r]) L = lossf(pv[r], tv[r], mv[r]);
    if (isposv[r]) {
      atomicAdd(&pos_sum[b], L);
      atomicAdd(&npos_arr[b], 1u);
    }
    // wave-aggregated candidate append
    unsigned long long mvote = __ballot(candv[r] ? 1 : 0);
    if (candv[r]) {
      int lane = threadIdx.x & 63;
      unsigned rank = (unsigned)__popcll(mvote & ((1ull << lane) - 1ull));
      int leader = __ffsll((unsigned long long)mvote) - 1;
      unsigned base = 0;
      if (lane == leader)
        base = atomicAdd(&cand_cnt[b], (unsigned)__popcll(mvote));
      base = __shfl(base, leader, 64);
      unsigned p = base + rank;
      if (p < cap) {
        size_t o = (size_t)b * cap + p;
        g_keys[o] = keyv[r];
        g_idxs[o] = i0 + (unsigned)r;
        g_loss[o] = L;
      }
    }
  }
}

__global__ __launch_bounds__(256) void passB(
    const unsigned* __restrict__ cand_cnt, const unsigned* __restrict__ npos_arr,
    const unsigned* __restrict__ g_keys, const unsigned* __restrict__ g_idxs,
    const float* __restrict__ g_loss, float* __restrict__ neg_total,
    unsigned cap)
{
  const int b = blockIdx.x;
  const int tid = threadIdx.x;

  __shared__ unsigned sk[CAP];        // 61440 B
  __shared__ unsigned redu[256];
  __shared__ float   redf[256];
  __shared__ unsigned s_bcnt;
  __shared__ unsigned s_bidx[BCAP];
  __shared__ float    s_bloss[BCAP];
  __shared__ float    s_f;
  __shared__ unsigned s_u;

  unsigned cnt = cand_cnt[b];
  if (cnt > cap) cnt = cap;
  const unsigned* Gk = g_keys + (size_t)b * cap;
  const unsigned* Gi = g_idxs + (size_t)b * cap;
  const float*    Gl = g_loss + (size_t)b * cap;

  for (unsigned e = tid; e < cnt; e += 256) sk[e] = Gk[e];
  __syncthreads();

  auto countGe = [&](unsigned v) -> unsigned {
    unsigned c = 0;
    for (unsigned e = tid; e < cnt; e += 256) c += (sk[e] >= v) ? 1u : 0u;
    redu[tid] = c; __syncthreads();
    for (int s = 128; s > 0; s >>= 1) { if (tid < s) redu[tid] += redu[tid + s]; __syncthreads(); }
    unsigned r = redu[0]; __syncthreads();
    return r;
  };

  const bool take_all = (cnt <= KSEL);
  unsigned v = 0, need = 0;
  if (!take_all) {
    unsigned lo = THRESH_KEY, hi = (1u << 23) - 1u;   // countGe(lo)=cnt>=KSEL
    while (lo < hi) {
      unsigned mid = lo + (hi - lo + 1u) / 2u;
      if (countGe(mid) >= KSEL) lo = mid; else hi = mid - 1u;
    }
    v = lo;
    unsigned c_gt = countGe(v + 1u);     // < KSEL by maximality
    need = KSEL - c_gt;
  }

  // sum of losses with key > v (or all, if take_all)
  {
    float s = 0.0f;
    for (unsigned e = tid; e < cnt; e += 256) {
      bool g = take_all || (sk[e] > v);
      if (g) s += Gl[e];
    }
    redf[tid] = s; __syncthreads();
    for (int st = 128; st > 0; st >>= 1) { if (tid < st) redf[tid] += redf[tid + st]; __syncthreads(); }
  }
  float sum_gt = redf[0];
  __syncthreads();

  // boundary (key == v): take `need` lowest-index entries (XLA top_k tie-break)
  if (tid == 0) s_bcnt = 0;
  __syncthreads();
  if (!take_all) {
    for (unsigned e = tid; e < cnt; e += 256) {
      if (sk[e] == v) {
        unsigned p = atomicAdd(&s_bcnt, 1u);
        if (p < BCAP) { s_bidx[p] = Gi[e]; s_bloss[p] = Gl[e]; }
      }
    }
  }
  __syncthreads();
  if (tid == 0) {
    float se = 0.0f; unsigned idxcut = 0xffffffffu;
    if (!take_all) {
      unsigned ceq = s_bcnt; if (ceq > BCAP) ceq = BCAP;
      unsigned m = (need < ceq) ? need : ceq;
      for (unsigned a = 0; a < m; ++a) {           // partial selection sort by idx asc
        unsigned best = a;
        for (unsigned q = a + 1; q < ceq; ++q)
          if (s_bidx[q] < s_bidx[best]) best = q;
        unsigned ti = s_bidx[a]; s_bidx[a] = s_bidx[best]; s_bidx[best] = ti;
        float tl = s_bloss[a]; s_bloss[a] = s_bloss[best]; s_bloss[best] = tl;
        se += s_bloss[a];
      }
      if (m > 0) idxcut = s_bidx[m - 1];
    }
    s_f = se; s_u = idxcut;
  }
  __syncthreads();
  float sum_eq = s_f;
  unsigned idxcut = s_u;
  __syncthreads();

  float total = sum_gt + sum_eq;
  unsigned nsel = take_all ? cnt : KSEL;

  unsigned np = npos_arr[b];
  unsigned k = (np > 0u) ? ((100u * np < KSEL) ? 100u * np : KSEL) : 100u;

  float result;
  if (k >= nsel) {
    result = total;                     // the always-taken path for this data
  } else {
    // exact sum of k largest losses among selected (value-threshold; losses >= 0)
    auto selp = [&](unsigned e) -> bool {
      if (take_all) return true;
      unsigned kk = sk[e];
      return (kk > v) || (kk == v && Gi[e] <= idxcut);
    };
    auto countLossGe = [&](unsigned w) -> unsigned {
      unsigned c = 0;
      for (unsigned e = tid; e < cnt; e += 256)
        if (selp(e) && __float_as_uint(Gl[e]) >= w) c++;
      redu[tid] = c; __syncthreads();
      for (int s = 128; s > 0; s >>= 1) { if (tid < s) redu[tid] += redu[tid + s]; __syncthreads(); }
      unsigned r = redu[0]; __syncthreads();
      return r;
    };
    unsigned lo = 0u, hi = 0x7f7fffffu;
    while (lo < hi) {
      unsigned mid = lo + (hi - lo + 1u) / 2u;
      if (countLossGe(mid) >= k) lo = mid; else hi = mid - 1u;
    }
    unsigned cgt = countLossGe(lo + 1u);
    float s2 = 0.0f;
    for (unsigned e = tid; e < cnt; e += 256)
      if (selp(e) && __float_as_uint(Gl[e]) > lo) s2 += Gl[e];
    redf[tid] = s2; __syncthreads();
    for (int st = 128; st > 0; st >>= 1) { if (tid < st) redf[tid] += redf[tid + st]; __syncthreads(); }
    result = redf[0] + (float)(k - cgt) * __uint_as_float(lo);
    __syncthreads();
  }

  if (tid == 0) neg_total[b] = result;
}

__global__ void passC(const float* __restrict__ pos_sum,
                      const unsigned* __restrict__ npos_arr,
                      const float* __restrict__ neg_total,
                      float* __restrict__ out)
{
  if (threadIdx.x == 0 && blockIdx.x == 0) {
    float ps = 0.0f, ns = 0.0f;
    for (int b = 0; b < BATCH; ++b) {
      unsigned np = npos_arr[b];
      float denom = (np > 0u) ? fmaxf((float)np, 1.0f) : 1.0f;
      ps += pos_sum[b] / denom;
      ns += neg_total[b] / denom;
    }
    out[0] = ps / (float)BATCH;
    out[1] = ns / (float)BATCH;
  }
}

extern "C" void kernel_launch(void* const* d_in, const int* in_sizes, int n_in,
                              void* d_out, int out_size, void* d_ws, size_t ws_size,
                              hipStream_t stream)
{
  const float* pred   = (const float*)d_in[0];
  const float* target = (const float*)d_in[1];
  const float* mask   = (const float*)d_in[2];
  float* out = (float*)d_out;

  // workspace layout: 256B header + 3 candidate arrays of BATCH*cap each.
  // Clamp cap to what ws_size actually provides (OOB writes could fault the
  // device); full accuracy needs cap == CAP (~2.95 MB total).
  size_t avail = (ws_size > 256) ? (ws_size - 256) : 0;
  unsigned cap = (unsigned)(avail / ((size_t)BATCH * 12));
  if (cap > CAP) cap = CAP;
  if (cap == 0 || out_size < 2) {
    hipMemsetAsync(d_out, 0, sizeof(float) * (out_size > 0 ? out_size : 1), stream);
    return;
  }

  char* ws = (char*)d_ws;
  float*    pos_sum  = (float*)(ws);
  unsigned* npos_arr = (unsigned*)(ws + 64);
  unsigned* cand_cnt = (unsigned*)(ws + 128);
  float*    neg_tot  = (float*)(ws + 192);
  unsigned* g_keys   = (unsigned*)(ws + 256);
  unsigned* g_idxs   = g_keys + (size_t)BATCH * cap;
  float*    g_loss   = (float*)(g_idxs + (size_t)BATCH * cap);

  // per-sample PRNG keys: fold-like split of key(42) => threefry((0,42),(0,b))
  KeyPairs kp;
  for (unsigned b = 0; b < BATCH; ++b) {
    unsigned o0, o1;
    tf2x32(0u, 42u, 0u, b, o0, o1);
    kp.k[2 * b] = o0; kp.k[2 * b + 1] = o1;
  }

  hipMemsetAsync(d_ws, 0, 256, stream);

  dim3 gA(NPTS / (256u * 4u), BATCH);   // 864 x 16, exact (no tail)
  passA<<<gA, 256, 0, stream>>>(pred, target, mask, pos_sum, npos_arr,
                                cand_cnt, g_keys, g_idxs, g_loss, cap, kp);
  passB<<<BATCH, 256, 0, stream>>>(cand_cnt, npos_arr, g_keys, g_idxs, g_loss,
                                   neg_tot, cap);
  passC<<<1, 64, 0, stream>>>(pos_sum, npos_arr, neg_tot, out);
}

// Round 4
// 143.712 us; speedup vs baseline: 11.1293x; 11.1293x over previous
//
#include <hip/hip_runtime.h>
#include <stdint.h>

// DetectionLoss for B=16, N=884736. Output: [cls_pos_loss, cls_neg_loss].
//
// R3 verified bit-exact PRNG/selection (absmax=0.0). R3 bottleneck: 146k
// return-value global atomics on ONE cache line (counters 4B apart) ->
// 1543us at 0.5% HBM. R4: block-level LDS aggregation, one global atomic
// per block per quantity, 256B-padded per-sample counter lines.

#define BATCH 16
#define NPTS 884736u
#define THRESH_KEY 8266976u   // keep keys >= this (tail fraction 0.01450)
#define CAP 15360u            // candidate capacity/sample (mean ~12825, sd ~112)
#define BCAP 64
#define KSEL 10000u
#define HDR 4096              // 16 samples x 256B line

// per-sample header line at hdr + b*256:
//   +0 f32 pos_sum, +4 u32 npos, +8 u32 cand_cnt, +12 f32 neg_tot

struct KeyPairs { unsigned k[2 * BATCH]; };

__host__ __device__ __forceinline__ void tf2x32(unsigned k0, unsigned k1,
                                                unsigned x0, unsigned x1,
                                                unsigned& o0, unsigned& o1)
{
  unsigned ks0 = k0, ks1 = k1, ks2 = k0 ^ k1 ^ 0x1BD11BDAu;
  x0 += ks0; x1 += ks1;
#define TF_R(r) { x0 += x1; x1 = (x1 << (r)) | (x1 >> (32 - (r))); x1 ^= x0; }
  TF_R(13) TF_R(15) TF_R(26) TF_R(6)
  x0 += ks1; x1 += ks2 + 1u;
  TF_R(17) TF_R(29) TF_R(16) TF_R(24)
  x0 += ks2; x1 += ks0 + 2u;
  TF_R(13) TF_R(15) TF_R(26) TF_R(6)
  x0 += ks0; x1 += ks1 + 3u;
  TF_R(17) TF_R(29) TF_R(16) TF_R(24)
  x0 += ks1; x1 += ks2 + 4u;
  TF_R(13) TF_R(15) TF_R(26) TF_R(6)
  x0 += ks2; x1 += ks0 + 5u;
#undef TF_R
  o0 = x0; o1 = x1;
}

__device__ __forceinline__ float lossf(float x, float t, float m)
{
  float p = 1.0f / (1.0f + expf(-x));
  p = fminf(fmaxf(p, 1e-4f), 1.0f - 1e-4f);
  bool is_pos = (t == 1.0f);
  float alpha = is_pos ? 0.75f : 0.25f;
  float pw = is_pos ? (1.0f - p) : p;
  float bce = fmaxf(x, 0.0f) - x * t + log1pf(expf(-fabsf(x)));
  float L = (m == 0.0f) ? alpha * pw * pw * bce : 0.0f;
  if (is_pos && p < 0.8f) L *= 4.0f;
  if (!is_pos && p > 0.5f) {
    float w = 1.5f + fminf(fmaxf((p - 0.5f) * 5.0f, 0.0f), 1.0f) * 0.5f;
    L *= w;
  }
  return L;
}

__global__ __launch_bounds__(256) void passA(
    const float* __restrict__ pred, const float* __restrict__ target,
    const float* __restrict__ mask, char* __restrict__ hdr,
    unsigned* __restrict__ g_keys, unsigned* __restrict__ g_idxs,
    float* __restrict__ g_loss, unsigned cap, KeyPairs kp)
{
  const int b = blockIdx.y;
  const int tid = threadIdx.x;
  const unsigned i0 = (blockIdx.x * 256u + tid) * 4u;
  const size_t off = (size_t)b * NPTS + i0;
  const unsigned k0 = kp.k[2 * b], k1 = kp.k[2 * b + 1];

  float4 t4 = *reinterpret_cast<const float4*>(target + off);
  float tv[4] = { t4.x, t4.y, t4.z, t4.w };

  unsigned keyv[4];
#pragma unroll
  for (int r = 0; r < 4; ++r) {
    unsigned o0, o1;
    tf2x32(k0, k1, 0u, i0 + (unsigned)r, o0, o1);
    keyv[r] = (o0 ^ o1) >> 9;
  }

  bool isposv[4], candv[4];
  bool any = false;
#pragma unroll
  for (int r = 0; r < 4; ++r) {
    isposv[r] = (tv[r] == 1.0f);
    candv[r] = (tv[r] == 0.0f) && (keyv[r] >= THRESH_KEY);
    any |= (isposv[r] | candv[r]);
  }

  float pv[4] = {0.f,0.f,0.f,0.f}, mv[4] = {0.f,0.f,0.f,0.f};
  if (any) {
    float4 p4 = *reinterpret_cast<const float4*>(pred + off);
    float4 m4 = *reinterpret_cast<const float4*>(mask + off);
    pv[0]=p4.x; pv[1]=p4.y; pv[2]=p4.z; pv[3]=p4.w;
    mv[0]=m4.x; mv[1]=m4.y; mv[2]=m4.z; mv[3]=m4.w;
  }

  // per-thread compaction
  float psum = 0.0f; unsigned pcnt = 0, ccnt = 0;
  unsigned ckey[4], cidx[4]; float closs[4];
#pragma unroll
  for (int r = 0; r < 4; ++r) {
    if (isposv[r] | candv[r]) {
      float L = lossf(pv[r], tv[r], mv[r]);
      if (isposv[r]) { psum += L; pcnt++; }
      else { ckey[ccnt] = keyv[r]; cidx[ccnt] = i0 + (unsigned)r; closs[ccnt] = L; ccnt++; }
    }
  }

  // block-level aggregation (LDS), then one global atomic per quantity
  __shared__ unsigned s_total, s_gbase, s_pcnt;
  __shared__ float s_psum;
  if (tid == 0) { s_total = 0; s_pcnt = 0; s_psum = 0.0f; }
  __syncthreads();
  unsigned my_off = 0;
  if (ccnt) my_off = atomicAdd(&s_total, ccnt);
  if (pcnt) { atomicAdd(&s_psum, psum); atomicAdd(&s_pcnt, pcnt); }
  __syncthreads();
  if (tid == 0) {
    char* line = hdr + (size_t)b * 256;
    unsigned t = s_total;
    s_gbase = t ? atomicAdd((unsigned*)(line + 8), t) : 0u;
    if (s_pcnt) {
      atomicAdd((float*)(line + 0), s_psum);
      atomicAdd((unsigned*)(line + 4), s_pcnt);
    }
  }
  __syncthreads();
  unsigned gb = s_gbase + my_off;
  for (unsigned j = 0; j < ccnt; ++j) {
    unsigned p = gb + j;
    if (p < cap) {
      size_t o = (size_t)b * cap + p;
      g_keys[o] = ckey[j];
      g_idxs[o] = cidx[j];
      g_loss[o] = closs[j];
    }
  }
}

__global__ __launch_bounds__(256) void passB(
    const char* __restrict__ hdr_ro, char* __restrict__ hdr_w,
    const unsigned* __restrict__ g_keys, const unsigned* __restrict__ g_idxs,
    const float* __restrict__ g_loss, unsigned cap)
{
  const int b = blockIdx.x;
  const int tid = threadIdx.x;
  const char* line = hdr_ro + (size_t)b * 256;

  __shared__ unsigned sk[CAP];        // 61440 B
  __shared__ unsigned redu[256];
  __shared__ float   redf[256];
  __shared__ unsigned s_bcnt;
  __shared__ unsigned s_bidx[BCAP];
  __shared__ float    s_bloss[BCAP];
  __shared__ float    s_f;
  __shared__ unsigned s_u;

  unsigned cnt = *(const unsigned*)(line + 8);
  if (cnt > cap) cnt = cap;
  const unsigned* Gk = g_keys + (size_t)b * cap;
  const unsigned* Gi = g_idxs + (size_t)b * cap;
  const float*    Gl = g_loss + (size_t)b * cap;

  for (unsigned e = tid; e < cnt; e += 256) sk[e] = Gk[e];
  __syncthreads();

  auto countGe = [&](unsigned v) -> unsigned {
    unsigned c = 0;
    for (unsigned e = tid; e < cnt; e += 256) c += (sk[e] >= v) ? 1u : 0u;
    redu[tid] = c; __syncthreads();
    for (int s = 128; s > 0; s >>= 1) { if (tid < s) redu[tid] += redu[tid + s]; __syncthreads(); }
    unsigned r = redu[0]; __syncthreads();
    return r;
  };

  const bool take_all = (cnt <= KSEL);
  unsigned v = 0, need = 0;
  if (!take_all) {
    unsigned lo = THRESH_KEY, hi = (1u << 23) - 1u;
    while (lo < hi) {
      unsigned mid = lo + (hi - lo + 1u) / 2u;
      if (countGe(mid) >= KSEL) lo = mid; else hi = mid - 1u;
    }
    v = lo;
    unsigned c_gt = countGe(v + 1u);
    need = KSEL - c_gt;
  }

  {
    float s = 0.0f;
    for (unsigned e = tid; e < cnt; e += 256) {
      bool g = take_all || (sk[e] > v);
      if (g) s += Gl[e];
    }
    redf[tid] = s; __syncthreads();
    for (int st = 128; st > 0; st >>= 1) { if (tid < st) redf[tid] += redf[tid + st]; __syncthreads(); }
  }
  float sum_gt = redf[0];
  __syncthreads();

  if (tid == 0) s_bcnt = 0;
  __syncthreads();
  if (!take_all) {
    for (unsigned e = tid; e < cnt; e += 256) {
      if (sk[e] == v) {
        unsigned p = atomicAdd(&s_bcnt, 1u);
        if (p < BCAP) { s_bidx[p] = Gi[e]; s_bloss[p] = Gl[e]; }
      }
    }
  }
  __syncthreads();
  if (tid == 0) {
    float se = 0.0f; unsigned idxcut = 0xffffffffu;
    if (!take_all) {
      unsigned ceq = s_bcnt; if (ceq > BCAP) ceq = BCAP;
      unsigned m = (need < ceq) ? need : ceq;
      for (unsigned a = 0; a < m; ++a) {
        unsigned best = a;
        for (unsigned q = a + 1; q < ceq; ++q)
          if (s_bidx[q] < s_bidx[best]) best = q;
        unsigned ti = s_bidx[a]; s_bidx[a] = s_bidx[best]; s_bidx[best] = ti;
        float tl = s_bloss[a]; s_bloss[a] = s_bloss[best]; s_bloss[best] = tl;
        se += s_bloss[a];
      }
      if (m > 0) idxcut = s_bidx[m - 1];
    }
    s_f = se; s_u = idxcut;
  }
  __syncthreads();
  float sum_eq = s_f;
  unsigned idxcut = s_u;
  __syncthreads();

  float total = sum_gt + sum_eq;
  unsigned nsel = take_all ? cnt : KSEL;

  unsigned np = *(const unsigned*)(line + 4);
  unsigned k = (np > 0u) ? ((100u * np < KSEL) ? 100u * np : KSEL) : 100u;

  float result;
  if (k >= nsel) {
    result = total;
  } else {
    auto selp = [&](unsigned e) -> bool {
      if (take_all) return true;
      unsigned kk = sk[e];
      return (kk > v) || (kk == v && Gi[e] <= idxcut);
    };
    auto countLossGe = [&](unsigned w) -> unsigned {
      unsigned c = 0;
      for (unsigned e = tid; e < cnt; e += 256)
        if (selp(e) && __float_as_uint(Gl[e]) >= w) c++;
      redu[tid] = c; __syncthreads();
      for (int s = 128; s > 0; s >>= 1) { if (tid < s) redu[tid] += redu[tid + s]; __syncthreads(); }
      unsigned r = redu[0]; __syncthreads();
      return r;
    };
    unsigned lo = 0u, hi = 0x7f7fffffu;
    while (lo < hi) {
      unsigned mid = lo + (hi - lo + 1u) / 2u;
      if (countLossGe(mid) >= k) lo = mid; else hi = mid - 1u;
    }
    unsigned cgt = countLossGe(lo + 1u);
    float s2 = 0.0f;
    for (unsigned e = tid; e < cnt; e += 256)
      if (selp(e) && __float_as_uint(Gl[e]) > lo) s2 += Gl[e];
    redf[tid] = s2; __syncthreads();
    for (int st = 128; st > 0; st >>= 1) { if (tid < st) redf[tid] += redf[tid + st]; __syncthreads(); }
    result = redf[0] + (float)(k - cgt) * __uint_as_float(lo);
    __syncthreads();
  }

  if (tid == 0) *(float*)(hdr_w + (size_t)b * 256 + 12) = result;
}

__global__ void passC(const char* __restrict__ hdr, float* __restrict__ out)
{
  if (threadIdx.x == 0 && blockIdx.x == 0) {
    float ps = 0.0f, ns = 0.0f;
    for (int b = 0; b < BATCH; ++b) {
      const char* line = hdr + (size_t)b * 256;
      unsigned np = *(const unsigned*)(line + 4);
      float denom = (np > 0u) ? fmaxf((float)np, 1.0f) : 1.0f;
      ps += (*(const float*)(line + 0)) / denom;
      ns += (*(const float*)(line + 12)) / denom;
    }
    out[0] = ps / (float)BATCH;
    out[1] = ns / (float)BATCH;
  }
}

extern "C" void kernel_launch(void* const* d_in, const int* in_sizes, int n_in,
                              void* d_out, int out_size, void* d_ws, size_t ws_size,
                              hipStream_t stream)
{
  const float* pred   = (const float*)d_in[0];
  const float* target = (const float*)d_in[1];
  const float* mask   = (const float*)d_in[2];
  float* out = (float*)d_out;

  size_t avail = (ws_size > HDR) ? (ws_size - HDR) : 0;
  unsigned cap = (unsigned)(avail / ((size_t)BATCH * 12));
  if (cap > CAP) cap = CAP;
  if (cap == 0 || out_size < 2) {
    hipMemsetAsync(d_out, 0, sizeof(float) * (out_size > 0 ? out_size : 1), stream);
    return;
  }

  char* ws = (char*)d_ws;
  char* hdr = ws;
  unsigned* g_keys = (unsigned*)(ws + HDR);
  unsigned* g_idxs = g_keys + (size_t)BATCH * cap;
  float*    g_loss = (float*)(g_idxs + (size_t)BATCH * cap);

  KeyPairs kp;
  for (unsigned b = 0; b < BATCH; ++b) {
    unsigned o0, o1;
    tf2x32(0u, 42u, 0u, b, o0, o1);
    kp.k[2 * b] = o0; kp.k[2 * b + 1] = o1;
  }

  hipMemsetAsync(hdr, 0, HDR, stream);

  dim3 gA(NPTS / (256u * 4u), BATCH);   // 864 x 16, exact (no tail)
  passA<<<gA, 256, 0, stream>>>(pred, target, mask, hdr,
                                g_keys, g_idxs, g_loss, cap, kp);
  passB<<<BATCH, 256, 0, stream>>>(hdr, hdr, g_keys, g_idxs, g_loss, cap);
  passC<<<1, 64, 0, stream>>>(hdr, out);
}